// Round 1
// baseline (562.214 us; speedup 1.0000x reference)
//
#include <hip/hip_runtime.h>
#include <hip/hip_bf16.h>

#define NB    65536
#define NT    5
#define NOBS  128
#define NACT  32
#define NH    64

typedef __attribute__((ext_vector_type(8))) short bf16x8;
typedef __attribute__((ext_vector_type(4))) float f32x4;

__device__ __forceinline__ float rcp_fast(float x) { return __builtin_amdgcn_rcpf(x); }
// sigmoid / tanh via v_exp + v_rcp (no IEEE div sequence)
__device__ __forceinline__ float sigf(float x) { return rcp_fast(1.0f + __expf(-x)); }
__device__ __forceinline__ float tanh_fast(float x) { return 1.0f - 2.0f * rcp_fast(__expf(2.0f * x) + 1.0f); }

__device__ __forceinline__ unsigned short f2b(float x) {
  __hip_bfloat16 h = __float2bfloat16(x);
  return *(unsigned short*)&h;
}
__device__ __forceinline__ float b2f(unsigned short u) {
  __hip_bfloat16 h = *(__hip_bfloat16*)&u;
  return __bfloat162float(h);
}
__device__ __forceinline__ void split_bf16(float x, unsigned short& h, unsigned short& l) {
  h = f2b(x);
  l = f2b(x - b2f(h));
}

// ---------------- K0: prepare all weight-derived tensors --------------------
__global__ __launch_bounds__(256) void k0_prep(
    const float* __restrict__ fk, const float* __restrict__ bk,
    const float* __restrict__ W1, const float* __restrict__ W2,
    const float* __restrict__ ln0g, const float* __restrict__ ln0b,
    const float* __restrict__ b1,
    unsigned int* __restrict__ fkT, unsigned int* __restrict__ bkT,
    unsigned short* __restrict__ w1h, unsigned short* __restrict__ w1l,
    unsigned short* __restrict__ w2h, unsigned short* __restrict__ w2l,
    float* __restrict__ u1, float* __restrict__ vb1) {
  const int bx = blockIdx.x;
  if (bx < 64) {
    const int g  = threadIdx.x;          // 0..255 column (gate-unit)
    const int k0 = bx * 2;               // even row
    unsigned int flo = f2b(fk[(k0 + 0) * 256 + g]);
    unsigned int fhi = f2b(fk[(k0 + 1) * 256 + g]);
    unsigned int blo = f2b(bk[(k0 + 0) * 256 + g]);
    unsigned int bhi = f2b(bk[(k0 + 1) * 256 + g]);
    fkT[g * 64 + bx] = flo | (fhi << 16);
    bkT[g * 64 + bx] = blo | (bhi << 16);
    return;
  }
  const int id = (bx - 64) * 256 + threadIdx.x;   // 0..2047
  if (id < 1024) {
    const int f = id >> 6, l = id & 63;
    const int kb = f >> 2, nt = f & 3;
    const int q = l >> 4, l16 = l & 15;
    const int n = nt * 16 + l16;
    bf16x8 vh, vl;
#pragma unroll
    for (int j = 0; j < 8; ++j) {
      const int k = kb * 32 + q * 8 + j;
      float wg = ln0g[k] * W1[k * 64 + n];
      unsigned short h, lo;
      split_bf16(wg, h, lo);
      vh[j] = (short)h; vl[j] = (short)lo;
    }
    *(bf16x8*)&w1h[(f * 64 + l) * 8] = vh;
    *(bf16x8*)&w1l[(f * 64 + l) * 8] = vl;
  } else if (id < 1792) {
    const int f = (id - 1024) >> 6, l = id & 63;
    const int kb = f >> 2, nt = f & 3;
    const int q = l >> 4, l16 = l & 15;
    const int n = nt * 16 + l16;
    bf16x8 vh, vl;
#pragma unroll
    for (int j = 0; j < 8; ++j) {
      const int k = kb * 32 + q * 8 + j;   // < 96
      float wv = W2[k * 64 + n];
      unsigned short h, lo;
      split_bf16(wv, h, lo);
      vh[j] = (short)h; vl[j] = (short)lo;
    }
    *(bf16x8*)&w2h[(f * 64 + l) * 8] = vh;
    *(bf16x8*)&w2l[(f * 64 + l) * 8] = vl;
  } else if (id < 1856) {
    const int n = id - 1792;               // 0..63
    float u = 0.0f, vb = 0.0f;
    for (int k = 0; k < 128; ++k) {
      float wv = W1[k * 64 + n];
      u  += ln0g[k] * wv;
      vb += ln0b[k] * wv;
    }
    u1[n]  = u;
    vb1[n] = vb + b1[n];
  }
}

// ---------------- K1: fused MLP via bf16 MFMA (split-precision) -------------
__global__ __launch_bounds__(256, 2) void k1_mlp(
    const float* __restrict__ ud, const float* __restrict__ action,
    const unsigned short* __restrict__ w1h, const unsigned short* __restrict__ w1l,
    const unsigned short* __restrict__ w2h, const unsigned short* __restrict__ w2l,
    const float* __restrict__ u1, const float* __restrict__ vb1,
    const float* __restrict__ gb2, const float* __restrict__ ln1g,
    const float* __restrict__ ln1b, const float* __restrict__ ln2g,
    const float* __restrict__ ln2b,
    unsigned short* __restrict__ hin) {
  const int wave = threadIdx.x >> 6;
  const int lane = threadIdx.x & 63;
  const int quad = lane >> 4;
  const int l16  = lane & 15;
  const int base = (blockIdx.x * 4 + wave) * 16;

  __shared__ __align__(16) unsigned short lds[4][4][2048];
  unsigned short* xh  = &lds[wave][0][0];
  unsigned short* xl  = &lds[wave][1][0];
  unsigned short* x2h = &lds[wave][2][0];
  unsigned short* x2l = &lds[wave][3][0];

  float u1v[4], vbv[4], g1v[4], c1v[4], b2v[4], g2v[4], c2v[4];
#pragma unroll
  for (int nt = 0; nt < 4; ++nt) {
    const int col = nt * 16 + l16;
    u1v[nt] = u1[col];  vbv[nt] = vb1[col];
    g1v[nt] = ln1g[col]; c1v[nt] = ln1b[col];
    b2v[nt] = gb2[col];
    g2v[nt] = ln2g[col]; c2v[nt] = ln2b[col];
  }

  {
    const int arow = lane >> 2, ag = lane & 3;
    const float* ap = &action[(size_t)(base + arow) * NACT + ag * 8];
    float4 a0 = *(const float4*)ap;
    float4 a1 = *(const float4*)(ap + 4);
    float av[8] = {a0.x, a0.y, a0.z, a0.w, a1.x, a1.y, a1.z, a1.w};
    bf16x8 vh, vl;
#pragma unroll
    for (int j = 0; j < 8; ++j) {
      unsigned short h, lo;
      split_bf16(av[j], h, lo);
      vh[j] = (short)h; vl[j] = (short)lo;
    }
    const int idx = arow * 128 + (((8 + ag) ^ (arow & 15)) << 3);
    *(bf16x8*)&x2h[idx] = vh;
    *(bf16x8*)&x2l[idx] = vl;
  }

#pragma unroll
  for (int r = 0; r < 16; ++r) {
    float2 xx = *(const float2*)&ud[(size_t)(base + r) * NOBS + 2 * lane];
    unsigned short h0, l0, h1, l1;
    split_bf16(xx.x, h0, l0);
    split_bf16(xx.y, h1, l1);
    const int di = r * 64 + (((lane >> 2) ^ (r & 15)) << 2) + (lane & 3);
    ((unsigned int*)xh)[di] = (unsigned int)h0 | ((unsigned int)h1 << 16);
    ((unsigned int*)xl)[di] = (unsigned int)l0 | ((unsigned int)l1 << 16);
  }

  bf16x8 W1hf[16], W1lf[16];
#pragma unroll
  for (int f = 0; f < 16; ++f) {
    W1hf[f] = *(const bf16x8*)&w1h[(f * 64 + lane) * 8];
    W1lf[f] = *(const bf16x8*)&w1l[(f * 64 + lane) * 8];
  }

  bf16x8 ones;
#pragma unroll
  for (int j = 0; j < 8; ++j) ones[j] = (short)0x3F80;

  f32x4 acc[4], s_acc, q_acc;
#pragma unroll
  for (int nt = 0; nt < 4; ++nt) acc[nt] = 0.0f;
  s_acc = 0.0f; q_acc = 0.0f;

#pragma unroll
  for (int kb = 0; kb < 4; ++kb) {
    const int ai = l16 * 128 + (((kb * 4 + quad) ^ l16) << 3);
    bf16x8 Ah = *(const bf16x8*)&xh[ai];
    bf16x8 Al = *(const bf16x8*)&xl[ai];
    bf16x8 Asq;
#pragma unroll
    for (int j = 0; j < 8; ++j) {
      unsigned int uu = ((unsigned int)(unsigned short)Ah[j]) << 16;
      float v = __uint_as_float(uu);
      v *= v;
      Asq[j] = (short)(unsigned short)(__float_as_uint(v) >> 16);
    }
    s_acc = __builtin_amdgcn_mfma_f32_16x16x32_bf16(Ah, ones, s_acc, 0, 0, 0);
    s_acc = __builtin_amdgcn_mfma_f32_16x16x32_bf16(Al, ones, s_acc, 0, 0, 0);
    q_acc = __builtin_amdgcn_mfma_f32_16x16x32_bf16(Asq, ones, q_acc, 0, 0, 0);
#pragma unroll
    for (int nt = 0; nt < 4; ++nt) {
      const int f = kb * 4 + nt;
      acc[nt] = __builtin_amdgcn_mfma_f32_16x16x32_bf16(Ah, W1hf[f], acc[nt], 0, 0, 0);
      acc[nt] = __builtin_amdgcn_mfma_f32_16x16x32_bf16(Ah, W1lf[f], acc[nt], 0, 0, 0);
      acc[nt] = __builtin_amdgcn_mfma_f32_16x16x32_bf16(Al, W1hf[f], acc[nt], 0, 0, 0);
    }
  }

  float inv0[4], ivm[4];
#pragma unroll
  for (int r = 0; r < 4; ++r) {
    float m   = s_acc[r] * (1.0f / 128.0f);
    float var = q_acc[r] * (1.0f / 128.0f) - m * m;
    float inv = rsqrtf(var + 1e-12f);
    inv0[r] = inv;
    ivm[r]  = inv * m;
  }
  float y[4][4];
#pragma unroll
  for (int nt = 0; nt < 4; ++nt)
#pragma unroll
    for (int r = 0; r < 4; ++r)
      y[nt][r] = fmaf(inv0[r], acc[nt][r], fmaf(-ivm[r], u1v[nt], vbv[nt]));

  float m1[4], i1[4];
#pragma unroll
  for (int r = 0; r < 4; ++r) {
    float s1 = y[0][r] + y[1][r] + y[2][r] + y[3][r];
    float q1 = y[0][r] * y[0][r] + y[1][r] * y[1][r] +
               y[2][r] * y[2][r] + y[3][r] * y[3][r];
#pragma unroll
    for (int off = 1; off <= 8; off <<= 1) {
      s1 += __shfl_xor(s1, off, 64);
      q1 += __shfl_xor(q1, off, 64);
    }
    float mm = s1 * (1.0f / 64.0f);
    m1[r] = mm;
    i1[r] = rsqrtf(q1 * (1.0f / 64.0f) - mm * mm + 1e-12f);
  }

#pragma unroll
  for (int nt = 0; nt < 4; ++nt)
#pragma unroll
    for (int r = 0; r < 4; ++r) {
      float x1 = fmaxf(0.0f, fmaf((y[nt][r] - m1[r]) * i1[r], g1v[nt], c1v[nt]));
      unsigned short h, lo;
      split_bf16(x1, h, lo);
      const int row = quad * 4 + r;
      const int idx = row * 128 + (((nt * 2 + (l16 >> 3)) ^ (row & 15)) << 3) + (l16 & 7);
      x2h[idx] = h;
      x2l[idx] = lo;
    }

  f32x4 acc2[4];
#pragma unroll
  for (int nt = 0; nt < 4; ++nt) acc2[nt] = 0.0f;

#pragma unroll
  for (int kb = 0; kb < 3; ++kb) {
    bf16x8 w2hf[4], w2lf[4];
#pragma unroll
    for (int nt = 0; nt < 4; ++nt) {
      const int f = kb * 4 + nt;
      w2hf[nt] = *(const bf16x8*)&w2h[(f * 64 + lane) * 8];
      w2lf[nt] = *(const bf16x8*)&w2l[(f * 64 + lane) * 8];
    }
    const int ai = l16 * 128 + (((kb * 4 + quad) ^ l16) << 3);
    bf16x8 Ah = *(const bf16x8*)&x2h[ai];
    bf16x8 Al = *(const bf16x8*)&x2l[ai];
#pragma unroll
    for (int nt = 0; nt < 4; ++nt) {
      acc2[nt] = __builtin_amdgcn_mfma_f32_16x16x32_bf16(Ah, w2hf[nt], acc2[nt], 0, 0, 0);
      acc2[nt] = __builtin_amdgcn_mfma_f32_16x16x32_bf16(Ah, w2lf[nt], acc2[nt], 0, 0, 0);
      acc2[nt] = __builtin_amdgcn_mfma_f32_16x16x32_bf16(Al, w2hf[nt], acc2[nt], 0, 0, 0);
    }
  }

  float y2[4][4];
#pragma unroll
  for (int nt = 0; nt < 4; ++nt)
#pragma unroll
    for (int r = 0; r < 4; ++r)
      y2[nt][r] = acc2[nt][r] + b2v[nt];

  float m2[4], i2[4];
#pragma unroll
  for (int r = 0; r < 4; ++r) {
    float s2 = y2[0][r] + y2[1][r] + y2[2][r] + y2[3][r];
    float q2 = y2[0][r] * y2[0][r] + y2[1][r] * y2[1][r] +
               y2[2][r] * y2[2][r] + y2[3][r] * y2[3][r];
#pragma unroll
    for (int off = 1; off <= 8; off <<= 1) {
      s2 += __shfl_xor(s2, off, 64);
      q2 += __shfl_xor(q2, off, 64);
    }
    float mm = s2 * (1.0f / 64.0f);
    m2[r] = mm;
    i2[r] = rsqrtf(q2 * (1.0f / 64.0f) - mm * mm + 1e-12f);
  }

#pragma unroll
  for (int nt = 0; nt < 4; ++nt)
#pragma unroll
    for (int r = 0; r < 4; ++r) {
      float o = fmaxf(0.0f, fmaf((y2[nt][r] - m2[r]) * i2[r], g2v[nt], c2v[nt]));
      const int row = quad * 4 + r;
      hin[(size_t)(base + row) * NH + nt * 16 + l16] = f2b(o);
    }
}

// ---------------- K23: fused bidirectional LSTM + LN3/conv/mask -------------
// grid NB/32. Block = 4 waves, 32 batches, BOTH directions.
// VALU-bound kernel (prev: VALUBusy 70%, MfmaUtil 9%). This revision:
//  - sigmoid/tanh use v_rcp instead of IEEE div sequence (5 divs/unit/step)
//  - forget bias + gate biases folded into MFMA accumulator init
//  - packed v_cvt_pk_bf16_f32 replaces two software-RTNE f2b per unit/step
//  - hA double-buffered -> 1 barrier/step instead of 2
//  - final LN/conv reduction processes 2 batches interleaved (shuffle-chain ILP)
//  - LDS 48 KB, __launch_bounds__(256,3): 3 blocks/CU
__global__ __launch_bounds__(256, 3) void k23_lstm_final(
    const unsigned short* __restrict__ hin,
    const unsigned short* __restrict__ fkT, const float* __restrict__ fwb,
    const unsigned short* __restrict__ bkT, const float* __restrict__ bwb,
    const int* __restrict__ au,
    const float* __restrict__ ln3g, const float* __restrict__ ln3b,
    const float* __restrict__ conv_w, const float* __restrict__ conv_b,
    const float* __restrict__ mask, float* __restrict__ out) {
  const int tid  = threadIdx.x;
  const int w    = tid >> 6;
  const int lane = tid & 63;
  const int quad = lane >> 4;
  const int l16  = lane & 15;
  const int batch0 = blockIdx.x * 32;

  __shared__ __align__(16) unsigned short obuf[10 * 32 * 64];  // 40 KB
  __shared__ __align__(16) unsigned short hA[2][32 * 64];      //  8 KB

  const int u = w * 16 + l16;

  // per-lane sequence lengths
  const int aum0 = au[batch0 + l16];
  const int aum1 = au[batch0 + 16 + l16];
  int aur[8];
#pragma unroll
  for (int mt = 0; mt < 2; ++mt)
#pragma unroll
    for (int r = 0; r < 4; ++r)
      aur[mt * 4 + r] = au[batch0 + mt * 16 + quad * 4 + r];

  for (int dir = 0; dir < 2; ++dir) {
    const unsigned short* kT   = dir ? bkT : fkT;
    const float*          bias = dir ? bwb : fwb;

    bf16x8 Bf[4][4];
#pragma unroll
    for (int g = 0; g < 4; ++g) {
      const int n = g * 64 + u;
#pragma unroll
      for (int kb = 0; kb < 4; ++kb)
        Bf[g][kb] = *(const bf16x8*)&kT[n * 128 + kb * 32 + quad * 8];
    }
    // gate biases; FORGET_BIAS folded into the f-gate bias. These become the
    // MFMA accumulator init (bias is per-column == per-lane, same for all 4
    // C rows in a lane), removing 4 adds/unit/step.
    const float bg0 = bias[u], bg1 = bias[64 + u];
    const float bg2 = bias[128 + u] + 1.0f, bg3 = bias[192 + u];

    // zero h buffer 0 (t=4 barrier of the previous dir protects this write)
    *(float4*)&hA[0][tid * 8] = make_float4(0.f, 0.f, 0.f, 0.f);
    float c_s[8], h_s[8];
#pragma unroll
    for (int i = 0; i < 8; ++i) { c_s[i] = 0.0f; h_s[i] = 0.0f; }
    __syncthreads();                       // hA[0] zero visible

    // prefetch x fragments for t=0 (au >= 1 so t=0 always valid)
    bf16x8 Ax0[2], Ax1[2];
#pragma unroll
    for (int mt = 0; mt < 2; ++mt) {
      const int m = mt * 16 + l16;
      const int a = mt ? aum1 : aum0;
      const int st = dir ? (a - 1) : 0;
      const size_t rb = ((size_t)(batch0 + m) * NT + st) * NH;
      Ax0[mt] = *(const bf16x8*)&hin[rb + quad * 8];
      Ax1[mt] = *(const bf16x8*)&hin[rb + 32 + quad * 8];
    }

    int cur = 0;
    for (int t = 0; t < NT; ++t) {
      const int nxt = cur ^ 1;
      f32x4 acc[2][4];
#pragma unroll
      for (int mt = 0; mt < 2; ++mt) {
        acc[mt][0] = bg0; acc[mt][1] = bg1; acc[mt][2] = bg2; acc[mt][3] = bg3;
      }

#pragma unroll
      for (int mt = 0; mt < 2; ++mt) {
        const int m = mt * 16 + l16;
        bf16x8 Ah0 = *(const bf16x8*)&hA[cur][m * 64 + ((quad ^ (m & 7)) << 3)];
        bf16x8 Ah1 = *(const bf16x8*)&hA[cur][m * 64 + (((4 + quad) ^ (m & 7)) << 3)];
#pragma unroll
        for (int g = 0; g < 4; ++g) {
          acc[mt][g] = __builtin_amdgcn_mfma_f32_16x16x32_bf16(Ax0[mt], Bf[g][0], acc[mt][g], 0, 0, 0);
          acc[mt][g] = __builtin_amdgcn_mfma_f32_16x16x32_bf16(Ax1[mt], Bf[g][1], acc[mt][g], 0, 0, 0);
          acc[mt][g] = __builtin_amdgcn_mfma_f32_16x16x32_bf16(Ah0, Bf[g][2], acc[mt][g], 0, 0, 0);
          acc[mt][g] = __builtin_amdgcn_mfma_f32_16x16x32_bf16(Ah1, Bf[g][3], acc[mt][g], 0, 0, 0);
        }
      }

      // prefetch x fragments for t+1 (independent of h / barriers)
      if (t < NT - 1) {
        const int t2 = t + 1;
#pragma unroll
        for (int mt = 0; mt < 2; ++mt) {
          const int m = mt * 16 + l16;
          const int a = mt ? aum1 : aum0;
          const int st = dir ? ((t2 < a) ? (a - 1 - t2) : t2) : t2;
          const size_t rb = ((size_t)(batch0 + m) * NT + st) * NH;
          Ax0[mt] = *(const bf16x8*)&hin[rb + quad * 8];
          Ax1[mt] = *(const bf16x8*)&hin[rb + 32 + quad * 8];
        }
      }

      // epilogue writes go to hA[nxt]; hA[cur] reads above are protected by
      // the end-of-step barrier (no wave enters t+1 before all finish t).
#pragma unroll
      for (int mt = 0; mt < 2; ++mt) {
#pragma unroll
        for (int r = 0; r < 4; ++r) {
          const int idx = mt * 4 + r;
          const int bl = mt * 16 + quad * 4 + r;
          const int a  = aur[idx];
          float gi = acc[mt][0][r];
          float gj = acc[mt][1][r];
          float gf = acc[mt][2][r];   // forget bias already folded in
          float go = acc[mt][3][r];
          float nc = sigf(gf) * c_s[idx] + sigf(gi) * tanh_fast(gj);
          float nh = sigf(go) * tanh_fast(nc);
          bool valid = t < a;
          c_s[idx] = valid ? nc : c_s[idx];
          h_s[idx] = valid ? nh : h_s[idx];
          float outv = valid ? nh : 0.0f;
          int pos = dir ? (valid ? (a - 1 - t) : t) : t;
          unsigned int pk;
          asm("v_cvt_pk_bf16_f32 %0, %1, %2" : "=v"(pk) : "v"(outv), "v"(h_s[idx]));
          obuf[(dir * 5 + pos) * 2048 + bl * 64 + u] = (unsigned short)pk;
          hA[nxt][bl * 64 + (((u >> 3) ^ (bl & 7)) << 3) + (u & 7)] =
              (unsigned short)(pk >> 16);
        }
      }
      __syncthreads();   // hA[nxt] complete + hA[cur] reads done
      cur = nxt;
    }
  }

  // ---- fused final stage: LN over (T,2H), relu, conv dot, masked sum ----
  // 2 batches per iteration so the two 6-deep shuffle chains overlap.
  const float gl  = ln3g[lane],      gh  = ln3g[64 + lane];
  const float bl3 = ln3b[lane],      bh3 = ln3b[64 + lane];
  const float cwl = conv_w[lane],    cwh = conv_w[64 + lane];
  const float cb  = conv_b[0];

  for (int bb = w * 8; bb < w * 8 + 8; bb += 2) {
    float v0[2][NT], v1[2][NT];
#pragma unroll
    for (int u2 = 0; u2 < 2; ++u2)
#pragma unroll
      for (int p = 0; p < NT; ++p) {
        v0[u2][p] = b2f(obuf[p * 2048 + (bb + u2) * 64 + lane]);
        v1[u2][p] = b2f(obuf[(5 + p) * 2048 + (bb + u2) * 64 + lane]);
      }
    float s[2], q[2];
#pragma unroll
    for (int u2 = 0; u2 < 2; ++u2) {
      s[u2] = 0.0f; q[u2] = 0.0f;
#pragma unroll
      for (int p = 0; p < NT; ++p) {
        s[u2] += v0[u2][p] + v1[u2][p];
        q[u2] += v0[u2][p] * v0[u2][p] + v1[u2][p] * v1[u2][p];
      }
    }
#pragma unroll
    for (int off = 32; off; off >>= 1) {
      s[0] += __shfl_xor(s[0], off, 64);
      q[0] += __shfl_xor(q[0], off, 64);
      s[1] += __shfl_xor(s[1], off, 64);
      q[1] += __shfl_xor(q[1], off, 64);
    }
    float local[2], msum[2];
#pragma unroll
    for (int u2 = 0; u2 < 2; ++u2) {
      const int b = batch0 + bb + u2;
      float m   = s[u2] * (1.0f / 640.0f);
      float var = q[u2] * (1.0f / 640.0f) - m * m;
      float inv = __builtin_amdgcn_rsqf(var + 1e-12f);
      float acc = 0.0f, ms = 0.0f;
#pragma unroll
      for (int p = 0; p < NT; ++p) {
        float mk = mask[b * NT + p];
        ms += mk;
        float xf = fmaxf(0.0f, (v0[u2][p] - m) * inv * gl + bl3);
        float xb = fmaxf(0.0f, (v1[u2][p] - m) * inv * gh + bh3);
        acc += mk * (xf * cwl + xb * cwh);
      }
      local[u2] = acc; msum[u2] = ms;
    }
#pragma unroll
    for (int off = 32; off; off >>= 1) {
      local[0] += __shfl_xor(local[0], off, 64);
      local[1] += __shfl_xor(local[1], off, 64);
    }
    if (lane == 0) {
      out[batch0 + bb]     = local[0] + cb * msum[0];
      out[batch0 + bb + 1] = local[1] + cb * msum[1];
    }
  }
}

extern "C" void kernel_launch(void* const* d_in, const int* in_sizes, int n_in,
                              void* d_out, int out_size, void* d_ws, size_t ws_size,
                              hipStream_t stream) {
  const float* ud     = (const float*)d_in[0];
  const float* action = (const float*)d_in[1];
  const float* mask   = (const float*)d_in[2];
  const float* ln0g   = (const float*)d_in[3];
  const float* ln0b   = (const float*)d_in[4];
  const float* W1     = (const float*)d_in[5];
  const float* b1     = (const float*)d_in[6];
  const float* ln1g   = (const float*)d_in[7];
  const float* ln1b   = (const float*)d_in[8];
  const float* W2     = (const float*)d_in[9];
  const float* b2     = (const float*)d_in[10];
  const float* ln2g   = (const float*)d_in[11];
  const float* ln2b   = (const float*)d_in[12];
  const float* fwk    = (const float*)d_in[13];
  const float* fwb    = (const float*)d_in[14];
  const float* bwk    = (const float*)d_in[15];
  const float* bwb    = (const float*)d_in[16];
  const float* ln3g   = (const float*)d_in[17];
  const float* ln3b   = (const float*)d_in[18];
  const float* conv_w = (const float*)d_in[19];
  const float* conv_b = (const float*)d_in[20];
  const int*   au     = (const int*)d_in[21];

  const size_t n_hin = (size_t)NB * NT * NH;   // 20,971,520 elements
  unsigned short* wsu   = (unsigned short*)d_ws;
  unsigned short* hin   = wsu;
  unsigned short* fkT   = hin + n_hin;            // 32768
  unsigned short* bkT   = fkT + 32768;            // 32768
  unsigned short* w1h   = bkT + 32768;            // 8192
  unsigned short* w1l   = w1h + 8192;             // 8192
  unsigned short* w2h   = w1l + 8192;             // 6144
  unsigned short* w2l   = w2h + 6144;             // 6144
  float*          u1    = (float*)(w2l + 6144);   // 64
  float*          vb1   = u1 + 64;                // 64

  float* outf = (float*)d_out;

  k0_prep<<<72, 256, 0, stream>>>(fwk, bwk, W1, W2, ln0g, ln0b, b1,
                                  (unsigned int*)fkT, (unsigned int*)bkT,
                                  w1h, w1l, w2h, w2l, u1, vb1);
  k1_mlp<<<(NB * NT) / 64, 256, 0, stream>>>(ud, action, w1h, w1l, w2h, w2l,
                                             u1, vb1, b2, ln1g, ln1b, ln2g, ln2b,
                                             hin);
  k23_lstm_final<<<NB / 32, 256, 0, stream>>>(hin, fkT, fwb, bkT, bwb, au,
                                              ln3g, ln3b, conv_w, conv_b,
                                              mask, outf);
}

// Round 2
// 468.348 us; speedup vs baseline: 1.2004x; 1.2004x over previous
//
#include <hip/hip_runtime.h>
#include <hip/hip_bf16.h>

#define NB    65536
#define NT    5
#define NOBS  128
#define NACT  32
#define NH    64

typedef __attribute__((ext_vector_type(8))) short bf16x8;
typedef __attribute__((ext_vector_type(4))) float f32x4;

__device__ __forceinline__ float rcp_fast(float x) { return __builtin_amdgcn_rcpf(x); }
// sigmoid / tanh via v_exp + v_rcp (no IEEE div sequence)
__device__ __forceinline__ float sigf(float x) { return rcp_fast(1.0f + __expf(-x)); }
__device__ __forceinline__ float tanh_fast(float x) { return 1.0f - 2.0f * rcp_fast(__expf(2.0f * x) + 1.0f); }

__device__ __forceinline__ unsigned short f2b(float x) {
  __hip_bfloat16 h = __float2bfloat16(x);
  return *(unsigned short*)&h;
}
__device__ __forceinline__ float b2f(unsigned short u) {
  __hip_bfloat16 h = *(__hip_bfloat16*)&u;
  return __bfloat162float(h);
}
__device__ __forceinline__ void split_bf16(float x, unsigned short& h, unsigned short& l) {
  h = f2b(x);
  l = f2b(x - b2f(h));
}

// ---------------- K0: prepare all weight-derived tensors --------------------
__global__ __launch_bounds__(256) void k0_prep(
    const float* __restrict__ fk, const float* __restrict__ bk,
    const float* __restrict__ W1, const float* __restrict__ W2,
    const float* __restrict__ ln0g, const float* __restrict__ ln0b,
    const float* __restrict__ b1,
    unsigned int* __restrict__ fkT, unsigned int* __restrict__ bkT,
    unsigned short* __restrict__ w1h, unsigned short* __restrict__ w1l,
    unsigned short* __restrict__ w2h, unsigned short* __restrict__ w2l,
    float* __restrict__ u1, float* __restrict__ vb1) {
  const int bx = blockIdx.x;
  if (bx < 64) {
    const int g  = threadIdx.x;          // 0..255 column (gate-unit)
    const int k0 = bx * 2;               // even row
    unsigned int flo = f2b(fk[(k0 + 0) * 256 + g]);
    unsigned int fhi = f2b(fk[(k0 + 1) * 256 + g]);
    unsigned int blo = f2b(bk[(k0 + 0) * 256 + g]);
    unsigned int bhi = f2b(bk[(k0 + 1) * 256 + g]);
    fkT[g * 64 + bx] = flo | (fhi << 16);
    bkT[g * 64 + bx] = blo | (bhi << 16);
    return;
  }
  const int id = (bx - 64) * 256 + threadIdx.x;   // 0..2047
  if (id < 1024) {
    const int f = id >> 6, l = id & 63;
    const int kb = f >> 2, nt = f & 3;
    const int q = l >> 4, l16 = l & 15;
    const int n = nt * 16 + l16;
    bf16x8 vh, vl;
#pragma unroll
    for (int j = 0; j < 8; ++j) {
      const int k = kb * 32 + q * 8 + j;
      float wg = ln0g[k] * W1[k * 64 + n];
      unsigned short h, lo;
      split_bf16(wg, h, lo);
      vh[j] = (short)h; vl[j] = (short)lo;
    }
    *(bf16x8*)&w1h[(f * 64 + l) * 8] = vh;
    *(bf16x8*)&w1l[(f * 64 + l) * 8] = vl;
  } else if (id < 1792) {
    const int f = (id - 1024) >> 6, l = id & 63;
    const int kb = f >> 2, nt = f & 3;
    const int q = l >> 4, l16 = l & 15;
    const int n = nt * 16 + l16;
    bf16x8 vh, vl;
#pragma unroll
    for (int j = 0; j < 8; ++j) {
      const int k = kb * 32 + q * 8 + j;   // < 96
      float wv = W2[k * 64 + n];
      unsigned short h, lo;
      split_bf16(wv, h, lo);
      vh[j] = (short)h; vl[j] = (short)lo;
    }
    *(bf16x8*)&w2h[(f * 64 + l) * 8] = vh;
    *(bf16x8*)&w2l[(f * 64 + l) * 8] = vl;
  } else if (id < 1856) {
    const int n = id - 1792;               // 0..63
    float u = 0.0f, vb = 0.0f;
    for (int k = 0; k < 128; ++k) {
      float wv = W1[k * 64 + n];
      u  += ln0g[k] * wv;
      vb += ln0b[k] * wv;
    }
    u1[n]  = u;
    vb1[n] = vb + b1[n];
  }
}

// ---------------- K1: fused MLP via bf16 MFMA (split-precision) -------------
__global__ __launch_bounds__(256, 2) void k1_mlp(
    const float* __restrict__ ud, const float* __restrict__ action,
    const unsigned short* __restrict__ w1h, const unsigned short* __restrict__ w1l,
    const unsigned short* __restrict__ w2h, const unsigned short* __restrict__ w2l,
    const float* __restrict__ u1, const float* __restrict__ vb1,
    const float* __restrict__ gb2, const float* __restrict__ ln1g,
    const float* __restrict__ ln1b, const float* __restrict__ ln2g,
    const float* __restrict__ ln2b,
    unsigned short* __restrict__ hin) {
  const int wave = threadIdx.x >> 6;
  const int lane = threadIdx.x & 63;
  const int quad = lane >> 4;
  const int l16  = lane & 15;
  const int base = (blockIdx.x * 4 + wave) * 16;

  __shared__ __align__(16) unsigned short lds[4][4][2048];
  unsigned short* xh  = &lds[wave][0][0];
  unsigned short* xl  = &lds[wave][1][0];
  unsigned short* x2h = &lds[wave][2][0];
  unsigned short* x2l = &lds[wave][3][0];

  float u1v[4], vbv[4], g1v[4], c1v[4], b2v[4], g2v[4], c2v[4];
#pragma unroll
  for (int nt = 0; nt < 4; ++nt) {
    const int col = nt * 16 + l16;
    u1v[nt] = u1[col];  vbv[nt] = vb1[col];
    g1v[nt] = ln1g[col]; c1v[nt] = ln1b[col];
    b2v[nt] = gb2[col];
    g2v[nt] = ln2g[col]; c2v[nt] = ln2b[col];
  }

  {
    const int arow = lane >> 2, ag = lane & 3;
    const float* ap = &action[(size_t)(base + arow) * NACT + ag * 8];
    float4 a0 = *(const float4*)ap;
    float4 a1 = *(const float4*)(ap + 4);
    float av[8] = {a0.x, a0.y, a0.z, a0.w, a1.x, a1.y, a1.z, a1.w};
    bf16x8 vh, vl;
#pragma unroll
    for (int j = 0; j < 8; ++j) {
      unsigned short h, lo;
      split_bf16(av[j], h, lo);
      vh[j] = (short)h; vl[j] = (short)lo;
    }
    const int idx = arow * 128 + (((8 + ag) ^ (arow & 15)) << 3);
    *(bf16x8*)&x2h[idx] = vh;
    *(bf16x8*)&x2l[idx] = vl;
  }

#pragma unroll
  for (int r = 0; r < 16; ++r) {
    float2 xx = *(const float2*)&ud[(size_t)(base + r) * NOBS + 2 * lane];
    unsigned short h0, l0, h1, l1;
    split_bf16(xx.x, h0, l0);
    split_bf16(xx.y, h1, l1);
    const int di = r * 64 + (((lane >> 2) ^ (r & 15)) << 2) + (lane & 3);
    ((unsigned int*)xh)[di] = (unsigned int)h0 | ((unsigned int)h1 << 16);
    ((unsigned int*)xl)[di] = (unsigned int)l0 | ((unsigned int)l1 << 16);
  }

  bf16x8 W1hf[16], W1lf[16];
#pragma unroll
  for (int f = 0; f < 16; ++f) {
    W1hf[f] = *(const bf16x8*)&w1h[(f * 64 + lane) * 8];
    W1lf[f] = *(const bf16x8*)&w1l[(f * 64 + lane) * 8];
  }

  bf16x8 ones;
#pragma unroll
  for (int j = 0; j < 8; ++j) ones[j] = (short)0x3F80;

  f32x4 acc[4], s_acc, q_acc;
#pragma unroll
  for (int nt = 0; nt < 4; ++nt) acc[nt] = 0.0f;
  s_acc = 0.0f; q_acc = 0.0f;

#pragma unroll
  for (int kb = 0; kb < 4; ++kb) {
    const int ai = l16 * 128 + (((kb * 4 + quad) ^ l16) << 3);
    bf16x8 Ah = *(const bf16x8*)&xh[ai];
    bf16x8 Al = *(const bf16x8*)&xl[ai];
    bf16x8 Asq;
#pragma unroll
    for (int j = 0; j < 8; ++j) {
      unsigned int uu = ((unsigned int)(unsigned short)Ah[j]) << 16;
      float v = __uint_as_float(uu);
      v *= v;
      Asq[j] = (short)(unsigned short)(__float_as_uint(v) >> 16);
    }
    s_acc = __builtin_amdgcn_mfma_f32_16x16x32_bf16(Ah, ones, s_acc, 0, 0, 0);
    s_acc = __builtin_amdgcn_mfma_f32_16x16x32_bf16(Al, ones, s_acc, 0, 0, 0);
    q_acc = __builtin_amdgcn_mfma_f32_16x16x32_bf16(Asq, ones, q_acc, 0, 0, 0);
#pragma unroll
    for (int nt = 0; nt < 4; ++nt) {
      const int f = kb * 4 + nt;
      acc[nt] = __builtin_amdgcn_mfma_f32_16x16x32_bf16(Ah, W1hf[f], acc[nt], 0, 0, 0);
      acc[nt] = __builtin_amdgcn_mfma_f32_16x16x32_bf16(Ah, W1lf[f], acc[nt], 0, 0, 0);
      acc[nt] = __builtin_amdgcn_mfma_f32_16x16x32_bf16(Al, W1hf[f], acc[nt], 0, 0, 0);
    }
  }

  float inv0[4], ivm[4];
#pragma unroll
  for (int r = 0; r < 4; ++r) {
    float m   = s_acc[r] * (1.0f / 128.0f);
    float var = q_acc[r] * (1.0f / 128.0f) - m * m;
    float inv = rsqrtf(var + 1e-12f);
    inv0[r] = inv;
    ivm[r]  = inv * m;
  }
  float y[4][4];
#pragma unroll
  for (int nt = 0; nt < 4; ++nt)
#pragma unroll
    for (int r = 0; r < 4; ++r)
      y[nt][r] = fmaf(inv0[r], acc[nt][r], fmaf(-ivm[r], u1v[nt], vbv[nt]));

  float m1[4], i1[4];
#pragma unroll
  for (int r = 0; r < 4; ++r) {
    float s1 = y[0][r] + y[1][r] + y[2][r] + y[3][r];
    float q1 = y[0][r] * y[0][r] + y[1][r] * y[1][r] +
               y[2][r] * y[2][r] + y[3][r] * y[3][r];
#pragma unroll
    for (int off = 1; off <= 8; off <<= 1) {
      s1 += __shfl_xor(s1, off, 64);
      q1 += __shfl_xor(q1, off, 64);
    }
    float mm = s1 * (1.0f / 64.0f);
    m1[r] = mm;
    i1[r] = rsqrtf(q1 * (1.0f / 64.0f) - mm * mm + 1e-12f);
  }

#pragma unroll
  for (int nt = 0; nt < 4; ++nt)
#pragma unroll
    for (int r = 0; r < 4; ++r) {
      float x1 = fmaxf(0.0f, fmaf((y[nt][r] - m1[r]) * i1[r], g1v[nt], c1v[nt]));
      unsigned short h, lo;
      split_bf16(x1, h, lo);
      const int row = quad * 4 + r;
      const int idx = row * 128 + (((nt * 2 + (l16 >> 3)) ^ (row & 15)) << 3) + (l16 & 7);
      x2h[idx] = h;
      x2l[idx] = lo;
    }

  f32x4 acc2[4];
#pragma unroll
  for (int nt = 0; nt < 4; ++nt) acc2[nt] = 0.0f;

#pragma unroll
  for (int kb = 0; kb < 3; ++kb) {
    bf16x8 w2hf[4], w2lf[4];
#pragma unroll
    for (int nt = 0; nt < 4; ++nt) {
      const int f = kb * 4 + nt;
      w2hf[nt] = *(const bf16x8*)&w2h[(f * 64 + lane) * 8];
      w2lf[nt] = *(const bf16x8*)&w2l[(f * 64 + lane) * 8];
    }
    const int ai = l16 * 128 + (((kb * 4 + quad) ^ l16) << 3);
    bf16x8 Ah = *(const bf16x8*)&x2h[ai];
    bf16x8 Al = *(const bf16x8*)&x2l[ai];
#pragma unroll
    for (int nt = 0; nt < 4; ++nt) {
      acc2[nt] = __builtin_amdgcn_mfma_f32_16x16x32_bf16(Ah, w2hf[nt], acc2[nt], 0, 0, 0);
      acc2[nt] = __builtin_amdgcn_mfma_f32_16x16x32_bf16(Ah, w2lf[nt], acc2[nt], 0, 0, 0);
      acc2[nt] = __builtin_amdgcn_mfma_f32_16x16x32_bf16(Al, w2hf[nt], acc2[nt], 0, 0, 0);
    }
  }

  float y2[4][4];
#pragma unroll
  for (int nt = 0; nt < 4; ++nt)
#pragma unroll
    for (int r = 0; r < 4; ++r)
      y2[nt][r] = acc2[nt][r] + b2v[nt];

  float m2[4], i2[4];
#pragma unroll
  for (int r = 0; r < 4; ++r) {
    float s2 = y2[0][r] + y2[1][r] + y2[2][r] + y2[3][r];
    float q2 = y2[0][r] * y2[0][r] + y2[1][r] * y2[1][r] +
               y2[2][r] * y2[2][r] + y2[3][r] * y2[3][r];
#pragma unroll
    for (int off = 1; off <= 8; off <<= 1) {
      s2 += __shfl_xor(s2, off, 64);
      q2 += __shfl_xor(q2, off, 64);
    }
    float mm = s2 * (1.0f / 64.0f);
    m2[r] = mm;
    i2[r] = rsqrtf(q2 * (1.0f / 64.0f) - mm * mm + 1e-12f);
  }

#pragma unroll
  for (int nt = 0; nt < 4; ++nt)
#pragma unroll
    for (int r = 0; r < 4; ++r) {
      float o = fmaxf(0.0f, fmaf((y2[nt][r] - m2[r]) * i2[r], g2v[nt], c2v[nt]));
      const int row = quad * 4 + r;
      hin[(size_t)(base + row) * NH + nt * 16 + l16] = f2b(o);
    }
}

// ---------------- K23: fused bidirectional LSTM + LN3/conv/mask -------------
// grid NB/32. Block = 4 waves, 32 batches, BOTH directions.
// VALU-bound kernel. Current revision keeps the round-1 VALU reductions:
//  - sigmoid/tanh use v_rcp instead of IEEE div sequence (5 divs/unit/step)
//  - forget bias + gate biases folded into MFMA accumulator init
//  - packed v_cvt_pk_bf16_f32 replaces two software-RTNE f2b per unit/step
//  - hA double-buffered -> 1 barrier/step instead of 2
//  - final LN/conv reduction processes 2 batches interleaved (shuffle-chain ILP)
// __launch_bounds__(256,2): the (256,3) variant capped VGPR at 84 and spilled
// ~300 B/thread to scratch (WRITE_SIZE 256 KB -> 154 MB, dur 190 -> 220 us).
// Occupancy is LDS-limited to 3 blocks/CU at 48 KB anyway; do not constrain
// the allocator below its natural ~100-120 VGPR.
__global__ __launch_bounds__(256, 2) void k23_lstm_final(
    const unsigned short* __restrict__ hin,
    const unsigned short* __restrict__ fkT, const float* __restrict__ fwb,
    const unsigned short* __restrict__ bkT, const float* __restrict__ bwb,
    const int* __restrict__ au,
    const float* __restrict__ ln3g, const float* __restrict__ ln3b,
    const float* __restrict__ conv_w, const float* __restrict__ conv_b,
    const float* __restrict__ mask, float* __restrict__ out) {
  const int tid  = threadIdx.x;
  const int w    = tid >> 6;
  const int lane = tid & 63;
  const int quad = lane >> 4;
  const int l16  = lane & 15;
  const int batch0 = blockIdx.x * 32;

  __shared__ __align__(16) unsigned short obuf[10 * 32 * 64];  // 40 KB
  __shared__ __align__(16) unsigned short hA[2][32 * 64];      //  8 KB

  const int u = w * 16 + l16;

  // per-lane sequence lengths
  const int aum0 = au[batch0 + l16];
  const int aum1 = au[batch0 + 16 + l16];
  int aur[8];
#pragma unroll
  for (int mt = 0; mt < 2; ++mt)
#pragma unroll
    for (int r = 0; r < 4; ++r)
      aur[mt * 4 + r] = au[batch0 + mt * 16 + quad * 4 + r];

  for (int dir = 0; dir < 2; ++dir) {
    const unsigned short* kT   = dir ? bkT : fkT;
    const float*          bias = dir ? bwb : fwb;

    bf16x8 Bf[4][4];
#pragma unroll
    for (int g = 0; g < 4; ++g) {
      const int n = g * 64 + u;
#pragma unroll
      for (int kb = 0; kb < 4; ++kb)
        Bf[g][kb] = *(const bf16x8*)&kT[n * 128 + kb * 32 + quad * 8];
    }
    // gate biases; FORGET_BIAS folded into the f-gate bias. These become the
    // MFMA accumulator init (bias is per-column == per-lane, same for all 4
    // C rows in a lane), removing 4 adds/unit/step.
    const float bg0 = bias[u], bg1 = bias[64 + u];
    const float bg2 = bias[128 + u] + 1.0f, bg3 = bias[192 + u];

    // zero h buffer 0 (t=4 barrier of the previous dir protects this write)
    *(float4*)&hA[0][tid * 8] = make_float4(0.f, 0.f, 0.f, 0.f);
    float c_s[8], h_s[8];
#pragma unroll
    for (int i = 0; i < 8; ++i) { c_s[i] = 0.0f; h_s[i] = 0.0f; }
    __syncthreads();                       // hA[0] zero visible

    // prefetch x fragments for t=0 (au >= 1 so t=0 always valid)
    bf16x8 Ax0[2], Ax1[2];
#pragma unroll
    for (int mt = 0; mt < 2; ++mt) {
      const int m = mt * 16 + l16;
      const int a = mt ? aum1 : aum0;
      const int st = dir ? (a - 1) : 0;
      const size_t rb = ((size_t)(batch0 + m) * NT + st) * NH;
      Ax0[mt] = *(const bf16x8*)&hin[rb + quad * 8];
      Ax1[mt] = *(const bf16x8*)&hin[rb + 32 + quad * 8];
    }

    int cur = 0;
    for (int t = 0; t < NT; ++t) {
      const int nxt = cur ^ 1;
      f32x4 acc[2][4];
#pragma unroll
      for (int mt = 0; mt < 2; ++mt) {
        acc[mt][0] = bg0; acc[mt][1] = bg1; acc[mt][2] = bg2; acc[mt][3] = bg3;
      }

#pragma unroll
      for (int mt = 0; mt < 2; ++mt) {
        const int m = mt * 16 + l16;
        bf16x8 Ah0 = *(const bf16x8*)&hA[cur][m * 64 + ((quad ^ (m & 7)) << 3)];
        bf16x8 Ah1 = *(const bf16x8*)&hA[cur][m * 64 + (((4 + quad) ^ (m & 7)) << 3)];
#pragma unroll
        for (int g = 0; g < 4; ++g) {
          acc[mt][g] = __builtin_amdgcn_mfma_f32_16x16x32_bf16(Ax0[mt], Bf[g][0], acc[mt][g], 0, 0, 0);
          acc[mt][g] = __builtin_amdgcn_mfma_f32_16x16x32_bf16(Ax1[mt], Bf[g][1], acc[mt][g], 0, 0, 0);
          acc[mt][g] = __builtin_amdgcn_mfma_f32_16x16x32_bf16(Ah0, Bf[g][2], acc[mt][g], 0, 0, 0);
          acc[mt][g] = __builtin_amdgcn_mfma_f32_16x16x32_bf16(Ah1, Bf[g][3], acc[mt][g], 0, 0, 0);
        }
      }

      // prefetch x fragments for t+1 (independent of h / barriers)
      if (t < NT - 1) {
        const int t2 = t + 1;
#pragma unroll
        for (int mt = 0; mt < 2; ++mt) {
          const int m = mt * 16 + l16;
          const int a = mt ? aum1 : aum0;
          const int st = dir ? ((t2 < a) ? (a - 1 - t2) : t2) : t2;
          const size_t rb = ((size_t)(batch0 + m) * NT + st) * NH;
          Ax0[mt] = *(const bf16x8*)&hin[rb + quad * 8];
          Ax1[mt] = *(const bf16x8*)&hin[rb + 32 + quad * 8];
        }
      }

      // epilogue writes go to hA[nxt]; hA[cur] reads above are protected by
      // the end-of-step barrier (no wave enters t+1 before all finish t).
#pragma unroll
      for (int mt = 0; mt < 2; ++mt) {
#pragma unroll
        for (int r = 0; r < 4; ++r) {
          const int idx = mt * 4 + r;
          const int bl = mt * 16 + quad * 4 + r;
          const int a  = aur[idx];
          float gi = acc[mt][0][r];
          float gj = acc[mt][1][r];
          float gf = acc[mt][2][r];   // forget bias already folded in
          float go = acc[mt][3][r];
          float nc = sigf(gf) * c_s[idx] + sigf(gi) * tanh_fast(gj);
          float nh = sigf(go) * tanh_fast(nc);
          bool valid = t < a;
          c_s[idx] = valid ? nc : c_s[idx];
          h_s[idx] = valid ? nh : h_s[idx];
          float outv = valid ? nh : 0.0f;
          int pos = dir ? (valid ? (a - 1 - t) : t) : t;
          unsigned int pk;
          asm("v_cvt_pk_bf16_f32 %0, %1, %2" : "=v"(pk) : "v"(outv), "v"(h_s[idx]));
          obuf[(dir * 5 + pos) * 2048 + bl * 64 + u] = (unsigned short)pk;
          hA[nxt][bl * 64 + (((u >> 3) ^ (bl & 7)) << 3) + (u & 7)] =
              (unsigned short)(pk >> 16);
        }
      }
      __syncthreads();   // hA[nxt] complete + hA[cur] reads done
      cur = nxt;
    }
  }

  // ---- fused final stage: LN over (T,2H), relu, conv dot, masked sum ----
  // 2 batches per iteration so the two 6-deep shuffle chains overlap.
  const float gl  = ln3g[lane],      gh  = ln3g[64 + lane];
  const float bl3 = ln3b[lane],      bh3 = ln3b[64 + lane];
  const float cwl = conv_w[lane],    cwh = conv_w[64 + lane];
  const float cb  = conv_b[0];

  for (int bb = w * 8; bb < w * 8 + 8; bb += 2) {
    float v0[2][NT], v1[2][NT];
#pragma unroll
    for (int u2 = 0; u2 < 2; ++u2)
#pragma unroll
      for (int p = 0; p < NT; ++p) {
        v0[u2][p] = b2f(obuf[p * 2048 + (bb + u2) * 64 + lane]);
        v1[u2][p] = b2f(obuf[(5 + p) * 2048 + (bb + u2) * 64 + lane]);
      }
    float s[2], q[2];
#pragma unroll
    for (int u2 = 0; u2 < 2; ++u2) {
      s[u2] = 0.0f; q[u2] = 0.0f;
#pragma unroll
      for (int p = 0; p < NT; ++p) {
        s[u2] += v0[u2][p] + v1[u2][p];
        q[u2] += v0[u2][p] * v0[u2][p] + v1[u2][p] * v1[u2][p];
      }
    }
#pragma unroll
    for (int off = 32; off; off >>= 1) {
      s[0] += __shfl_xor(s[0], off, 64);
      q[0] += __shfl_xor(q[0], off, 64);
      s[1] += __shfl_xor(s[1], off, 64);
      q[1] += __shfl_xor(q[1], off, 64);
    }
    float local[2], msum[2];
#pragma unroll
    for (int u2 = 0; u2 < 2; ++u2) {
      const int b = batch0 + bb + u2;
      float m   = s[u2] * (1.0f / 640.0f);
      float var = q[u2] * (1.0f / 640.0f) - m * m;
      float inv = __builtin_amdgcn_rsqf(var + 1e-12f);
      float acc = 0.0f, ms = 0.0f;
#pragma unroll
      for (int p = 0; p < NT; ++p) {
        float mk = mask[b * NT + p];
        ms += mk;
        float xf = fmaxf(0.0f, (v0[u2][p] - m) * inv * gl + bl3);
        float xb = fmaxf(0.0f, (v1[u2][p] - m) * inv * gh + bh3);
        acc += mk * (xf * cwl + xb * cwh);
      }
      local[u2] = acc; msum[u2] = ms;
    }
#pragma unroll
    for (int off = 32; off; off >>= 1) {
      local[0] += __shfl_xor(local[0], off, 64);
      local[1] += __shfl_xor(local[1], off, 64);
    }
    if (lane == 0) {
      out[batch0 + bb]     = local[0] + cb * msum[0];
      out[batch0 + bb + 1] = local[1] + cb * msum[1];
    }
  }
}

extern "C" void kernel_launch(void* const* d_in, const int* in_sizes, int n_in,
                              void* d_out, int out_size, void* d_ws, size_t ws_size,
                              hipStream_t stream) {
  const float* ud     = (const float*)d_in[0];
  const float* action = (const float*)d_in[1];
  const float* mask   = (const float*)d_in[2];
  const float* ln0g   = (const float*)d_in[3];
  const float* ln0b   = (const float*)d_in[4];
  const float* W1     = (const float*)d_in[5];
  const float* b1     = (const float*)d_in[6];
  const float* ln1g   = (const float*)d_in[7];
  const float* ln1b   = (const float*)d_in[8];
  const float* W2     = (const float*)d_in[9];
  const float* b2     = (const float*)d_in[10];
  const float* ln2g   = (const float*)d_in[11];
  const float* ln2b   = (const float*)d_in[12];
  const float* fwk    = (const float*)d_in[13];
  const float* fwb    = (const float*)d_in[14];
  const float* bwk    = (const float*)d_in[15];
  const float* bwb    = (const float*)d_in[16];
  const float* ln3g   = (const float*)d_in[17];
  const float* ln3b   = (const float*)d_in[18];
  const float* conv_w = (const float*)d_in[19];
  const float* conv_b = (const float*)d_in[20];
  const int*   au     = (const int*)d_in[21];

  const size_t n_hin = (size_t)NB * NT * NH;   // 20,971,520 elements
  unsigned short* wsu   = (unsigned short*)d_ws;
  unsigned short* hin   = wsu;
  unsigned short* fkT   = hin + n_hin;            // 32768
  unsigned short* bkT   = fkT + 32768;            // 32768
  unsigned short* w1h   = bkT + 32768;            // 8192
  unsigned short* w1l   = w1h + 8192;             // 8192
  unsigned short* w2h   = w1l + 8192;             // 6144
  unsigned short* w2l   = w2h + 6144;             // 6144
  float*          u1    = (float*)(w2l + 6144);   // 64
  float*          vb1   = u1 + 64;                // 64

  float* outf = (float*)d_out;

  k0_prep<<<72, 256, 0, stream>>>(fwk, bwk, W1, W2, ln0g, ln0b, b1,
                                  (unsigned int*)fkT, (unsigned int*)bkT,
                                  w1h, w1l, w2h, w2l, u1, vb1);
  k1_mlp<<<(NB * NT) / 64, 256, 0, stream>>>(ud, action, w1h, w1l, w2h, w2l,
                                             u1, vb1, b2, ln1g, ln1b, ln2g, ln2b,
                                             hin);
  k23_lstm_final<<<NB / 32, 256, 0, stream>>>(hin, fkT, fwb, bkT, bwb, au,
                                              ln3g, ln3b, conv_w, conv_b,
                                              mask, outf);
}

// Round 3
// 452.797 us; speedup vs baseline: 1.2416x; 1.0343x over previous
//
#include <hip/hip_runtime.h>
#include <hip/hip_bf16.h>

#define NB    65536
#define NT    5
#define NOBS  128
#define NACT  32
#define NH    64

typedef __attribute__((ext_vector_type(8))) short bf16x8;
typedef __attribute__((ext_vector_type(4))) float f32x4;

__device__ __forceinline__ float rcp_fast(float x) { return __builtin_amdgcn_rcpf(x); }
// sigmoid / tanh via v_exp + v_rcp (no IEEE div sequence)
__device__ __forceinline__ float sigf(float x) { return rcp_fast(1.0f + __expf(-x)); }
__device__ __forceinline__ float tanh_fast(float x) { return 1.0f - 2.0f * rcp_fast(__expf(2.0f * x) + 1.0f); }

__device__ __forceinline__ unsigned short f2b(float x) {
  __hip_bfloat16 h = __float2bfloat16(x);
  return *(unsigned short*)&h;
}
__device__ __forceinline__ float b2f(unsigned short u) {
  __hip_bfloat16 h = *(__hip_bfloat16*)&u;
  return __bfloat162float(h);
}
__device__ __forceinline__ void split_bf16(float x, unsigned short& h, unsigned short& l) {
  h = f2b(x);
  l = f2b(x - b2f(h));
}

// ---------------- K0: prepare all weight-derived tensors --------------------
__global__ __launch_bounds__(256) void k0_prep(
    const float* __restrict__ fk, const float* __restrict__ bk,
    const float* __restrict__ W1, const float* __restrict__ W2,
    const float* __restrict__ ln0g, const float* __restrict__ ln0b,
    const float* __restrict__ b1,
    unsigned int* __restrict__ fkT, unsigned int* __restrict__ bkT,
    unsigned short* __restrict__ w1h, unsigned short* __restrict__ w1l,
    unsigned short* __restrict__ w2h, unsigned short* __restrict__ w2l,
    float* __restrict__ u1, float* __restrict__ vb1) {
  const int bx = blockIdx.x;
  if (bx < 64) {
    const int g  = threadIdx.x;          // 0..255 column (gate-unit)
    const int k0 = bx * 2;               // even row
    unsigned int flo = f2b(fk[(k0 + 0) * 256 + g]);
    unsigned int fhi = f2b(fk[(k0 + 1) * 256 + g]);
    unsigned int blo = f2b(bk[(k0 + 0) * 256 + g]);
    unsigned int bhi = f2b(bk[(k0 + 1) * 256 + g]);
    fkT[g * 64 + bx] = flo | (fhi << 16);
    bkT[g * 64 + bx] = blo | (bhi << 16);
    return;
  }
  const int id = (bx - 64) * 256 + threadIdx.x;   // 0..2047
  if (id < 1024) {
    const int f = id >> 6, l = id & 63;
    const int kb = f >> 2, nt = f & 3;
    const int q = l >> 4, l16 = l & 15;
    const int n = nt * 16 + l16;
    bf16x8 vh, vl;
#pragma unroll
    for (int j = 0; j < 8; ++j) {
      const int k = kb * 32 + q * 8 + j;
      float wg = ln0g[k] * W1[k * 64 + n];
      unsigned short h, lo;
      split_bf16(wg, h, lo);
      vh[j] = (short)h; vl[j] = (short)lo;
    }
    *(bf16x8*)&w1h[(f * 64 + l) * 8] = vh;
    *(bf16x8*)&w1l[(f * 64 + l) * 8] = vl;
  } else if (id < 1792) {
    const int f = (id - 1024) >> 6, l = id & 63;
    const int kb = f >> 2, nt = f & 3;
    const int q = l >> 4, l16 = l & 15;
    const int n = nt * 16 + l16;
    bf16x8 vh, vl;
#pragma unroll
    for (int j = 0; j < 8; ++j) {
      const int k = kb * 32 + q * 8 + j;   // < 96
      float wv = W2[k * 64 + n];
      unsigned short h, lo;
      split_bf16(wv, h, lo);
      vh[j] = (short)h; vl[j] = (short)lo;
    }
    *(bf16x8*)&w2h[(f * 64 + l) * 8] = vh;
    *(bf16x8*)&w2l[(f * 64 + l) * 8] = vl;
  } else if (id < 1856) {
    const int n = id - 1792;               // 0..63
    float u = 0.0f, vb = 0.0f;
    for (int k = 0; k < 128; ++k) {
      float wv = W1[k * 64 + n];
      u  += ln0g[k] * wv;
      vb += ln0b[k] * wv;
    }
    u1[n]  = u;
    vb1[n] = vb + b1[n];
  }
}

// ---------------- K1: fused MLP via bf16 MFMA (split-precision) -------------
// Latency-bound at 64 KB LDS (2 blocks/CU, occupancy 21%). This revision
// deletes the ud LDS staging entirely: the GEMM1 A-fragment for lane
// (quad,l16) is exactly ud[base+l16][kb*32+quad*8 .. +8] (the old XOR-swizzle
// write/read pair composes to identity on that mapping), so each lane loads
// its 32 floats directly from global and splits to bf16 hi/lo in registers.
// LN0 row-stats still come from the ones-B MFMAs on the same fragments.
// LDS 64 KB -> 32 KB (only the GEMM2 transpose buffer remains);
// __launch_bounds__(256,4) caps VGPR at 128 (natural ~120, no spill) ->
// 4 blocks/CU.
__global__ __launch_bounds__(256, 4) void k1_mlp(
    const float* __restrict__ ud, const float* __restrict__ action,
    const unsigned short* __restrict__ w1h, const unsigned short* __restrict__ w1l,
    const unsigned short* __restrict__ w2h, const unsigned short* __restrict__ w2l,
    const float* __restrict__ u1, const float* __restrict__ vb1,
    const float* __restrict__ gb2, const float* __restrict__ ln1g,
    const float* __restrict__ ln1b, const float* __restrict__ ln2g,
    const float* __restrict__ ln2b,
    unsigned short* __restrict__ hin) {
  const int wave = threadIdx.x >> 6;
  const int lane = threadIdx.x & 63;
  const int quad = lane >> 4;
  const int l16  = lane & 15;
  const int base = (blockIdx.x * 4 + wave) * 16;

  __shared__ __align__(16) unsigned short lds[4][2][2048];
  unsigned short* x2h = &lds[wave][0][0];
  unsigned short* x2l = &lds[wave][1][0];

  float u1v[4], vbv[4], g1v[4], c1v[4], b2v[4], g2v[4], c2v[4];
#pragma unroll
  for (int nt = 0; nt < 4; ++nt) {
    const int col = nt * 16 + l16;
    u1v[nt] = u1[col];  vbv[nt] = vb1[col];
    g1v[nt] = ln1g[col]; c1v[nt] = ln1b[col];
    b2v[nt] = gb2[col];
    g2v[nt] = ln2g[col]; c2v[nt] = ln2b[col];
  }

  {
    const int arow = lane >> 2, ag = lane & 3;
    const float* ap = &action[(size_t)(base + arow) * NACT + ag * 8];
    float4 a0 = *(const float4*)ap;
    float4 a1 = *(const float4*)(ap + 4);
    float av[8] = {a0.x, a0.y, a0.z, a0.w, a1.x, a1.y, a1.z, a1.w};
    bf16x8 vh, vl;
#pragma unroll
    for (int j = 0; j < 8; ++j) {
      unsigned short h, lo;
      split_bf16(av[j], h, lo);
      vh[j] = (short)h; vl[j] = (short)lo;
    }
    const int idx = arow * 128 + (((8 + ag) ^ (arow & 15)) << 3);
    *(bf16x8*)&x2h[idx] = vh;
    *(bf16x8*)&x2l[idx] = vl;
  }

  // direct global load of the GEMM1 A-fragments: lane (quad,l16) owns
  // row base+l16, cols kb*32 + quad*8 .. +8 (32-B aligned).
  const float* rp = &ud[(size_t)(base + l16) * NOBS + quad * 8];
  float4 cfa[4], cfb[4];
#pragma unroll
  for (int kb = 0; kb < 4; ++kb) {
    cfa[kb] = *(const float4*)(rp + kb * 32);
    cfb[kb] = *(const float4*)(rp + kb * 32 + 4);
  }

  bf16x8 W1hf[16], W1lf[16];
#pragma unroll
  for (int f = 0; f < 16; ++f) {
    W1hf[f] = *(const bf16x8*)&w1h[(f * 64 + lane) * 8];
    W1lf[f] = *(const bf16x8*)&w1l[(f * 64 + lane) * 8];
  }

  bf16x8 ones;
#pragma unroll
  for (int j = 0; j < 8; ++j) ones[j] = (short)0x3F80;

  f32x4 acc[4], s_acc, q_acc;
#pragma unroll
  for (int nt = 0; nt < 4; ++nt) acc[nt] = 0.0f;
  s_acc = 0.0f; q_acc = 0.0f;

#pragma unroll
  for (int kb = 0; kb < 4; ++kb) {
    const float xv[8] = {cfa[kb].x, cfa[kb].y, cfa[kb].z, cfa[kb].w,
                         cfb[kb].x, cfb[kb].y, cfb[kb].z, cfb[kb].w};
    bf16x8 Ah, Al, Asq;
#pragma unroll
    for (int j = 0; j < 8; ++j) {
      unsigned short h, lo;
      split_bf16(xv[j], h, lo);
      Ah[j] = (short)h; Al[j] = (short)lo;
      unsigned int uu = ((unsigned int)h) << 16;
      float v = __uint_as_float(uu);
      v *= v;
      Asq[j] = (short)(unsigned short)(__float_as_uint(v) >> 16);
    }
    s_acc = __builtin_amdgcn_mfma_f32_16x16x32_bf16(Ah, ones, s_acc, 0, 0, 0);
    s_acc = __builtin_amdgcn_mfma_f32_16x16x32_bf16(Al, ones, s_acc, 0, 0, 0);
    q_acc = __builtin_amdgcn_mfma_f32_16x16x32_bf16(Asq, ones, q_acc, 0, 0, 0);
#pragma unroll
    for (int nt = 0; nt < 4; ++nt) {
      const int f = kb * 4 + nt;
      acc[nt] = __builtin_amdgcn_mfma_f32_16x16x32_bf16(Ah, W1hf[f], acc[nt], 0, 0, 0);
      acc[nt] = __builtin_amdgcn_mfma_f32_16x16x32_bf16(Ah, W1lf[f], acc[nt], 0, 0, 0);
      acc[nt] = __builtin_amdgcn_mfma_f32_16x16x32_bf16(Al, W1hf[f], acc[nt], 0, 0, 0);
    }
  }

  float inv0[4], ivm[4];
#pragma unroll
  for (int r = 0; r < 4; ++r) {
    float m   = s_acc[r] * (1.0f / 128.0f);
    float var = q_acc[r] * (1.0f / 128.0f) - m * m;
    float inv = rsqrtf(var + 1e-12f);
    inv0[r] = inv;
    ivm[r]  = inv * m;
  }
  float y[4][4];
#pragma unroll
  for (int nt = 0; nt < 4; ++nt)
#pragma unroll
    for (int r = 0; r < 4; ++r)
      y[nt][r] = fmaf(inv0[r], acc[nt][r], fmaf(-ivm[r], u1v[nt], vbv[nt]));

  float m1[4], i1[4];
#pragma unroll
  for (int r = 0; r < 4; ++r) {
    float s1 = y[0][r] + y[1][r] + y[2][r] + y[3][r];
    float q1 = y[0][r] * y[0][r] + y[1][r] * y[1][r] +
               y[2][r] * y[2][r] + y[3][r] * y[3][r];
#pragma unroll
    for (int off = 1; off <= 8; off <<= 1) {
      s1 += __shfl_xor(s1, off, 64);
      q1 += __shfl_xor(q1, off, 64);
    }
    float mm = s1 * (1.0f / 64.0f);
    m1[r] = mm;
    i1[r] = rsqrtf(q1 * (1.0f / 64.0f) - mm * mm + 1e-12f);
  }

#pragma unroll
  for (int nt = 0; nt < 4; ++nt)
#pragma unroll
    for (int r = 0; r < 4; ++r) {
      float x1 = fmaxf(0.0f, fmaf((y[nt][r] - m1[r]) * i1[r], g1v[nt], c1v[nt]));
      unsigned short h, lo;
      split_bf16(x1, h, lo);
      const int row = quad * 4 + r;
      const int idx = row * 128 + (((nt * 2 + (l16 >> 3)) ^ (row & 15)) << 3) + (l16 & 7);
      x2h[idx] = h;
      x2l[idx] = lo;
    }

  f32x4 acc2[4];
#pragma unroll
  for (int nt = 0; nt < 4; ++nt) acc2[nt] = 0.0f;

#pragma unroll
  for (int kb = 0; kb < 3; ++kb) {
    bf16x8 w2hf[4], w2lf[4];
#pragma unroll
    for (int nt = 0; nt < 4; ++nt) {
      const int f = kb * 4 + nt;
      w2hf[nt] = *(const bf16x8*)&w2h[(f * 64 + lane) * 8];
      w2lf[nt] = *(const bf16x8*)&w2l[(f * 64 + lane) * 8];
    }
    const int ai = l16 * 128 + (((kb * 4 + quad) ^ l16) << 3);
    bf16x8 Ah = *(const bf16x8*)&x2h[ai];
    bf16x8 Al = *(const bf16x8*)&x2l[ai];
#pragma unroll
    for (int nt = 0; nt < 4; ++nt) {
      acc2[nt] = __builtin_amdgcn_mfma_f32_16x16x32_bf16(Ah, w2hf[nt], acc2[nt], 0, 0, 0);
      acc2[nt] = __builtin_amdgcn_mfma_f32_16x16x32_bf16(Ah, w2lf[nt], acc2[nt], 0, 0, 0);
      acc2[nt] = __builtin_amdgcn_mfma_f32_16x16x32_bf16(Al, w2hf[nt], acc2[nt], 0, 0, 0);
    }
  }

  float y2[4][4];
#pragma unroll
  for (int nt = 0; nt < 4; ++nt)
#pragma unroll
    for (int r = 0; r < 4; ++r)
      y2[nt][r] = acc2[nt][r] + b2v[nt];

  float m2[4], i2[4];
#pragma unroll
  for (int r = 0; r < 4; ++r) {
    float s2 = y2[0][r] + y2[1][r] + y2[2][r] + y2[3][r];
    float q2 = y2[0][r] * y2[0][r] + y2[1][r] * y2[1][r] +
               y2[2][r] * y2[2][r] + y2[3][r] * y2[3][r];
#pragma unroll
    for (int off = 1; off <= 8; off <<= 1) {
      s2 += __shfl_xor(s2, off, 64);
      q2 += __shfl_xor(q2, off, 64);
    }
    float mm = s2 * (1.0f / 64.0f);
    m2[r] = mm;
    i2[r] = rsqrtf(q2 * (1.0f / 64.0f) - mm * mm + 1e-12f);
  }

#pragma unroll
  for (int nt = 0; nt < 4; ++nt)
#pragma unroll
    for (int r = 0; r < 4; ++r) {
      float o = fmaxf(0.0f, fmaf((y2[nt][r] - m2[r]) * i2[r], g2v[nt], c2v[nt]));
      const int row = quad * 4 + r;
      hin[(size_t)(base + row) * NH + nt * 16 + l16] = f2b(o);
    }
}

// ---------------- K23: fused bidirectional LSTM + LN3/conv/mask -------------
// grid NB/32. Block = 4 waves, 32 batches, BOTH directions.
// VALU-bound kernel. Current revision keeps the round-1 VALU reductions:
//  - sigmoid/tanh use v_rcp instead of IEEE div sequence (5 divs/unit/step)
//  - forget bias + gate biases folded into MFMA accumulator init
//  - packed v_cvt_pk_bf16_f32 replaces two software-RTNE f2b per unit/step
//  - hA double-buffered -> 1 barrier/step instead of 2
//  - final LN/conv reduction processes 2 batches interleaved (shuffle-chain ILP)
// __launch_bounds__(256,2): the (256,3) variant capped VGPR at 84 and spilled
// ~300 B/thread to scratch (WRITE_SIZE 256 KB -> 154 MB, dur 190 -> 220 us).
// Occupancy is LDS-limited to 3 blocks/CU at 48 KB anyway; do not constrain
// the allocator below its natural ~100-120 VGPR.
__global__ __launch_bounds__(256, 2) void k23_lstm_final(
    const unsigned short* __restrict__ hin,
    const unsigned short* __restrict__ fkT, const float* __restrict__ fwb,
    const unsigned short* __restrict__ bkT, const float* __restrict__ bwb,
    const int* __restrict__ au,
    const float* __restrict__ ln3g, const float* __restrict__ ln3b,
    const float* __restrict__ conv_w, const float* __restrict__ conv_b,
    const float* __restrict__ mask, float* __restrict__ out) {
  const int tid  = threadIdx.x;
  const int w    = tid >> 6;
  const int lane = tid & 63;
  const int quad = lane >> 4;
  const int l16  = lane & 15;
  const int batch0 = blockIdx.x * 32;

  __shared__ __align__(16) unsigned short obuf[10 * 32 * 64];  // 40 KB
  __shared__ __align__(16) unsigned short hA[2][32 * 64];      //  8 KB

  const int u = w * 16 + l16;

  // per-lane sequence lengths
  const int aum0 = au[batch0 + l16];
  const int aum1 = au[batch0 + 16 + l16];
  int aur[8];
#pragma unroll
  for (int mt = 0; mt < 2; ++mt)
#pragma unroll
    for (int r = 0; r < 4; ++r)
      aur[mt * 4 + r] = au[batch0 + mt * 16 + quad * 4 + r];

  for (int dir = 0; dir < 2; ++dir) {
    const unsigned short* kT   = dir ? bkT : fkT;
    const float*          bias = dir ? bwb : fwb;

    bf16x8 Bf[4][4];
#pragma unroll
    for (int g = 0; g < 4; ++g) {
      const int n = g * 64 + u;
#pragma unroll
      for (int kb = 0; kb < 4; ++kb)
        Bf[g][kb] = *(const bf16x8*)&kT[n * 128 + kb * 32 + quad * 8];
    }
    // gate biases; FORGET_BIAS folded into the f-gate bias. These become the
    // MFMA accumulator init (bias is per-column == per-lane, same for all 4
    // C rows in a lane), removing 4 adds/unit/step.
    const float bg0 = bias[u], bg1 = bias[64 + u];
    const float bg2 = bias[128 + u] + 1.0f, bg3 = bias[192 + u];

    // zero h buffer 0 (t=4 barrier of the previous dir protects this write)
    *(float4*)&hA[0][tid * 8] = make_float4(0.f, 0.f, 0.f, 0.f);
    float c_s[8], h_s[8];
#pragma unroll
    for (int i = 0; i < 8; ++i) { c_s[i] = 0.0f; h_s[i] = 0.0f; }
    __syncthreads();                       // hA[0] zero visible

    // prefetch x fragments for t=0 (au >= 1 so t=0 always valid)
    bf16x8 Ax0[2], Ax1[2];
#pragma unroll
    for (int mt = 0; mt < 2; ++mt) {
      const int m = mt * 16 + l16;
      const int a = mt ? aum1 : aum0;
      const int st = dir ? (a - 1) : 0;
      const size_t rb = ((size_t)(batch0 + m) * NT + st) * NH;
      Ax0[mt] = *(const bf16x8*)&hin[rb + quad * 8];
      Ax1[mt] = *(const bf16x8*)&hin[rb + 32 + quad * 8];
    }

    int cur = 0;
    for (int t = 0; t < NT; ++t) {
      const int nxt = cur ^ 1;
      f32x4 acc[2][4];
#pragma unroll
      for (int mt = 0; mt < 2; ++mt) {
        acc[mt][0] = bg0; acc[mt][1] = bg1; acc[mt][2] = bg2; acc[mt][3] = bg3;
      }

#pragma unroll
      for (int mt = 0; mt < 2; ++mt) {
        const int m = mt * 16 + l16;
        bf16x8 Ah0 = *(const bf16x8*)&hA[cur][m * 64 + ((quad ^ (m & 7)) << 3)];
        bf16x8 Ah1 = *(const bf16x8*)&hA[cur][m * 64 + (((4 + quad) ^ (m & 7)) << 3)];
#pragma unroll
        for (int g = 0; g < 4; ++g) {
          acc[mt][g] = __builtin_amdgcn_mfma_f32_16x16x32_bf16(Ax0[mt], Bf[g][0], acc[mt][g], 0, 0, 0);
          acc[mt][g] = __builtin_amdgcn_mfma_f32_16x16x32_bf16(Ax1[mt], Bf[g][1], acc[mt][g], 0, 0, 0);
          acc[mt][g] = __builtin_amdgcn_mfma_f32_16x16x32_bf16(Ah0, Bf[g][2], acc[mt][g], 0, 0, 0);
          acc[mt][g] = __builtin_amdgcn_mfma_f32_16x16x32_bf16(Ah1, Bf[g][3], acc[mt][g], 0, 0, 0);
        }
      }

      // prefetch x fragments for t+1 (independent of h / barriers)
      if (t < NT - 1) {
        const int t2 = t + 1;
#pragma unroll
        for (int mt = 0; mt < 2; ++mt) {
          const int m = mt * 16 + l16;
          const int a = mt ? aum1 : aum0;
          const int st = dir ? ((t2 < a) ? (a - 1 - t2) : t2) : t2;
          const size_t rb = ((size_t)(batch0 + m) * NT + st) * NH;
          Ax0[mt] = *(const bf16x8*)&hin[rb + quad * 8];
          Ax1[mt] = *(const bf16x8*)&hin[rb + 32 + quad * 8];
        }
      }

      // epilogue writes go to hA[nxt]; hA[cur] reads above are protected by
      // the end-of-step barrier (no wave enters t+1 before all finish t).
#pragma unroll
      for (int mt = 0; mt < 2; ++mt) {
#pragma unroll
        for (int r = 0; r < 4; ++r) {
          const int idx = mt * 4 + r;
          const int bl = mt * 16 + quad * 4 + r;
          const int a  = aur[idx];
          float gi = acc[mt][0][r];
          float gj = acc[mt][1][r];
          float gf = acc[mt][2][r];   // forget bias already folded in
          float go = acc[mt][3][r];
          float nc = sigf(gf) * c_s[idx] + sigf(gi) * tanh_fast(gj);
          float nh = sigf(go) * tanh_fast(nc);
          bool valid = t < a;
          c_s[idx] = valid ? nc : c_s[idx];
          h_s[idx] = valid ? nh : h_s[idx];
          float outv = valid ? nh : 0.0f;
          int pos = dir ? (valid ? (a - 1 - t) : t) : t;
          unsigned int pk;
          asm("v_cvt_pk_bf16_f32 %0, %1, %2" : "=v"(pk) : "v"(outv), "v"(h_s[idx]));
          obuf[(dir * 5 + pos) * 2048 + bl * 64 + u] = (unsigned short)pk;
          hA[nxt][bl * 64 + (((u >> 3) ^ (bl & 7)) << 3) + (u & 7)] =
              (unsigned short)(pk >> 16);
        }
      }
      __syncthreads();   // hA[nxt] complete + hA[cur] reads done
      cur = nxt;
    }
  }

  // ---- fused final stage: LN over (T,2H), relu, conv dot, masked sum ----
  // 2 batches per iteration so the two 6-deep shuffle chains overlap.
  const float gl  = ln3g[lane],      gh  = ln3g[64 + lane];
  const float bl3 = ln3b[lane],      bh3 = ln3b[64 + lane];
  const float cwl = conv_w[lane],    cwh = conv_w[64 + lane];
  const float cb  = conv_b[0];

  for (int bb = w * 8; bb < w * 8 + 8; bb += 2) {
    float v0[2][NT], v1[2][NT];
#pragma unroll
    for (int u2 = 0; u2 < 2; ++u2)
#pragma unroll
      for (int p = 0; p < NT; ++p) {
        v0[u2][p] = b2f(obuf[p * 2048 + (bb + u2) * 64 + lane]);
        v1[u2][p] = b2f(obuf[(5 + p) * 2048 + (bb + u2) * 64 + lane]);
      }
    float s[2], q[2];
#pragma unroll
    for (int u2 = 0; u2 < 2; ++u2) {
      s[u2] = 0.0f; q[u2] = 0.0f;
#pragma unroll
      for (int p = 0; p < NT; ++p) {
        s[u2] += v0[u2][p] + v1[u2][p];
        q[u2] += v0[u2][p] * v0[u2][p] + v1[u2][p] * v1[u2][p];
      }
    }
#pragma unroll
    for (int off = 32; off; off >>= 1) {
      s[0] += __shfl_xor(s[0], off, 64);
      q[0] += __shfl_xor(q[0], off, 64);
      s[1] += __shfl_xor(s[1], off, 64);
      q[1] += __shfl_xor(q[1], off, 64);
    }
    float local[2], msum[2];
#pragma unroll
    for (int u2 = 0; u2 < 2; ++u2) {
      const int b = batch0 + bb + u2;
      float m   = s[u2] * (1.0f / 640.0f);
      float var = q[u2] * (1.0f / 640.0f) - m * m;
      float inv = __builtin_amdgcn_rsqf(var + 1e-12f);
      float acc = 0.0f, ms = 0.0f;
#pragma unroll
      for (int p = 0; p < NT; ++p) {
        float mk = mask[b * NT + p];
        ms += mk;
        float xf = fmaxf(0.0f, (v0[u2][p] - m) * inv * gl + bl3);
        float xb = fmaxf(0.0f, (v1[u2][p] - m) * inv * gh + bh3);
        acc += mk * (xf * cwl + xb * cwh);
      }
      local[u2] = acc; msum[u2] = ms;
    }
#pragma unroll
    for (int off = 32; off; off >>= 1) {
      local[0] += __shfl_xor(local[0], off, 64);
      local[1] += __shfl_xor(local[1], off, 64);
    }
    if (lane == 0) {
      out[batch0 + bb]     = local[0] + cb * msum[0];
      out[batch0 + bb + 1] = local[1] + cb * msum[1];
    }
  }
}

extern "C" void kernel_launch(void* const* d_in, const int* in_sizes, int n_in,
                              void* d_out, int out_size, void* d_ws, size_t ws_size,
                              hipStream_t stream) {
  const float* ud     = (const float*)d_in[0];
  const float* action = (const float*)d_in[1];
  const float* mask   = (const float*)d_in[2];
  const float* ln0g   = (const float*)d_in[3];
  const float* ln0b   = (const float*)d_in[4];
  const float* W1     = (const float*)d_in[5];
  const float* b1     = (const float*)d_in[6];
  const float* ln1g   = (const float*)d_in[7];
  const float* ln1b   = (const float*)d_in[8];
  const float* W2     = (const float*)d_in[9];
  const float* b2     = (const float*)d_in[10];
  const float* ln2g   = (const float*)d_in[11];
  const float* ln2b   = (const float*)d_in[12];
  const float* fwk    = (const float*)d_in[13];
  const float* fwb    = (const float*)d_in[14];
  const float* bwk    = (const float*)d_in[15];
  const float* bwb    = (const float*)d_in[16];
  const float* ln3g   = (const float*)d_in[17];
  const float* ln3b   = (const float*)d_in[18];
  const float* conv_w = (const float*)d_in[19];
  const float* conv_b = (const float*)d_in[20];
  const int*   au     = (const int*)d_in[21];

  const size_t n_hin = (size_t)NB * NT * NH;   // 20,971,520 elements
  unsigned short* wsu   = (unsigned short*)d_ws;
  unsigned short* hin   = wsu;
  unsigned short* fkT   = hin + n_hin;            // 32768
  unsigned short* bkT   = fkT + 32768;            // 32768
  unsigned short* w1h   = bkT + 32768;            // 8192
  unsigned short* w1l   = w1h + 8192;             // 8192
  unsigned short* w2h   = w1l + 8192;             // 6144
  unsigned short* w2l   = w2h + 6144;             // 6144
  float*          u1    = (float*)(w2l + 6144);   // 64
  float*          vb1   = u1 + 64;                // 64

  float* outf = (float*)d_out;

  k0_prep<<<72, 256, 0, stream>>>(fwk, bwk, W1, W2, ln0g, ln0b, b1,
                                  (unsigned int*)fkT, (unsigned int*)bkT,
                                  w1h, w1l, w2h, w2l, u1, vb1);
  k1_mlp<<<(NB * NT) / 64, 256, 0, stream>>>(ud, action, w1h, w1l, w2h, w2l,
                                             u1, vb1, b2, ln1g, ln1b, ln2g, ln2b,
                                             hin);
  k23_lstm_final<<<NB / 32, 256, 0, stream>>>(hin, fkT, fwb, bkT, bwb, au,
                                              ln3g, ln3b, conv_w, conv_b,
                                              mask, outf);
}